// Round 1
// baseline (103.694 us; speedup 1.0000x reference)
//
#include <hip/hip_runtime.h>

namespace {
constexpr int Hh = 16;
constexpr int Ll = 1024;
constexpr int Dd = 64;
constexpr int Cc = 64;                  // chunk length
constexpr int NCHUNK = Ll / Cc;         // 16
constexpr int SD = 68;                  // padded row stride (16B-aligned, bank-spread)
constexpr int KV_CHUNK = 128 * 64;      // floats per chunk state
constexpr int KV_TOTAL = Hh * NCHUNK * KV_CHUNK;
constexpr float PI_HALF = 1.5707963267948966f;
constexpr float EPSV = 1e-6f;
}

// Kernel 1: per (head, chunk) sums  KV[f][d] = sum_j w[j]*rk[j][f]*v[j][d],
// ksum[f] = sum_j w[j]*rk[j][f]   (f<64: w=sin, f>=64: w=cos; rk = relu(k))
__global__ __launch_bounds__(256)
void cosformer_chunk_sums(const float* __restrict__ kin,
                          const float* __restrict__ vin,
                          float* __restrict__ ws) {
    const int c = blockIdx.x, h = blockIdx.y;
    const int tid = threadIdx.x;
    __shared__ float rk[Cc * SD];
    __shared__ float vv[Cc * SD];
    __shared__ float wsn[Cc], wcs[Cc];

    const size_t gbase = ((size_t)h * Ll + (size_t)c * Cc) * Dd;
    #pragma unroll
    for (int i = 0; i < (Cc * Dd) / 256; ++i) {
        int e = i * 256 + tid;
        int j = e >> 6, d = e & 63;
        float kx = kin[gbase + e];
        rk[j * SD + d] = kx > 0.f ? kx : 0.f;
        vv[j * SD + d] = vin[gbase + e];
    }
    if (tid < Cc) {
        float th = PI_HALF * (float)(c * Cc + tid + 1) * (1.0f / (float)Ll);
        wsn[tid] = __sinf(th);
        wcs[tid] = __cosf(th);
    }
    __syncthreads();

    // thread tile: 8 f x 4 d
    const int tf = tid >> 4;      // 0..15
    const int td = tid & 15;      // 0..15
    const int f0 = tf * 8;        // 0..120
    const int fi = f0 & 63;
    const float* wp = (f0 < 64) ? wsn : wcs;

    float acc[8][4];
    #pragma unroll
    for (int r = 0; r < 8; ++r)
        #pragma unroll
        for (int x = 0; x < 4; ++x) acc[r][x] = 0.f;

    for (int j = 0; j < Cc; ++j) {
        float w = wp[j];
        const float4 va = *(const float4*)&vv[j * SD + td * 4];
        const float4 b0 = *(const float4*)&rk[j * SD + fi];
        const float4 b1 = *(const float4*)&rk[j * SD + fi + 4];
        float wk[8] = {w * b0.x, w * b0.y, w * b0.z, w * b0.w,
                       w * b1.x, w * b1.y, w * b1.z, w * b1.w};
        #pragma unroll
        for (int r = 0; r < 8; ++r) {
            acc[r][0] += wk[r] * va.x;
            acc[r][1] += wk[r] * va.y;
            acc[r][2] += wk[r] * va.z;
            acc[r][3] += wk[r] * va.w;
        }
    }
    float* kvout = ws + (size_t)(h * NCHUNK + c) * KV_CHUNK;
    #pragma unroll
    for (int r = 0; r < 8; ++r) {
        *(float4*)&kvout[(f0 + r) * Dd + td * 4] =
            make_float4(acc[r][0], acc[r][1], acc[r][2], acc[r][3]);
    }
    if (tid < 128) {
        const float* wp2 = (tid < 64) ? wsn : wcs;
        int f = tid & 63;
        float s = 0.f;
        for (int j = 0; j < Cc; ++j) s += wp2[j] * rk[j * SD + f];
        ws[(size_t)KV_TOTAL + (size_t)(h * NCHUNK + c) * 128 + tid] = s;
    }
}

// Kernel 2: per (head, chunk) output.
__global__ __launch_bounds__(256)
void cosformer_chunk_out(const float* __restrict__ qin,
                         const float* __restrict__ kin,
                         const float* __restrict__ vin,
                         const float* __restrict__ ws,
                         float* __restrict__ out) {
    const int c = blockIdx.x, h = blockIdx.y;
    const int tid = threadIdx.x;
    __shared__ float S[128 * 64];        // prefix state, stride 64 (float4-friendly)
    __shared__ float ksum[128];
    __shared__ float rq[Cc * SD], rk[Cc * SD], vv[Cc * SD];
    __shared__ float wsn[Cc], wcs[Cc];
    __shared__ float Am[Cc * SD];        // causal scores, zeros above diagonal
    __shared__ float dnm[Cc];

    // exclusive prefix of chunk states for chunks < c
    {
        float pacc[32];
        #pragma unroll
        for (int i = 0; i < 32; ++i) pacc[i] = 0.f;
        const float* kvb = ws + (size_t)h * NCHUNK * KV_CHUNK;
        for (int cp = 0; cp < c; ++cp) {
            const float* p = kvb + (size_t)cp * KV_CHUNK;
            #pragma unroll
            for (int i = 0; i < 32; ++i) pacc[i] += p[i * 256 + tid];
        }
        #pragma unroll
        for (int i = 0; i < 32; ++i) S[i * 256 + tid] = pacc[i];
    }
    if (tid < 128) {
        const float* k1b = ws + (size_t)KV_TOTAL + (size_t)h * NCHUNK * 128;
        float a = 0.f;
        for (int cp = 0; cp < c; ++cp) a += k1b[cp * 128 + tid];
        ksum[tid] = a;
    }
    const size_t gbase = ((size_t)h * Ll + (size_t)c * Cc) * Dd;
    #pragma unroll
    for (int i = 0; i < 16; ++i) {
        int e = i * 256 + tid;
        int j = e >> 6, d = e & 63;
        float qx = qin[gbase + e];
        rq[j * SD + d] = qx > 0.f ? qx : 0.f;
        float kx = kin[gbase + e];
        rk[j * SD + d] = kx > 0.f ? kx : 0.f;
        vv[j * SD + d] = vin[gbase + e];
    }
    if (tid < Cc) {
        float th = PI_HALF * (float)(c * Cc + tid + 1) * (1.0f / (float)Ll);
        wsn[tid] = __sinf(th);
        wcs[tid] = __cosf(th);
    }
    __syncthreads();

    // Phase A: scores. tid = l*4 + t, thread handles j = 4*jj + t
    {
        const int l = tid >> 2, t = tid & 3;
        const float sl = wsn[l], cl = wcs[l];
        float4 qr[16];
        #pragma unroll
        for (int d4 = 0; d4 < 16; ++d4)
            qr[d4] = *(const float4*)&rq[l * SD + d4 * 4];
        float dpart = 0.f;
        for (int jj = 0; jj < 16; ++jj) {
            int j = jj * 4 + t;
            float aval = 0.f;
            if (j <= l) {   // whole-wave execz skip for upper-triangular tiles
                float dot = 0.f;
                #pragma unroll
                for (int d4 = 0; d4 < 16; ++d4) {
                    float4 b = *(const float4*)&rk[j * SD + d4 * 4];
                    dot += qr[d4].x * b.x + qr[d4].y * b.y +
                           qr[d4].z * b.z + qr[d4].w * b.w;
                }
                aval = (sl * wsn[j] + cl * wcs[j]) * dot;
            }
            Am[l * SD + j] = aval;
            dpart += aval;
        }
        dpart += __shfl_down(dpart, 1, 4);
        dpart += __shfl_down(dpart, 2, 4);
        if (t == 0) {
            float dsv = 0.f, dcv = 0.f;
            for (int dp = 0; dp < 64; ++dp) {
                float qv = rq[l * SD + dp];
                dsv += qv * ksum[dp];
                dcv += qv * ksum[64 + dp];
            }
            float dn = dpart + sl * dsv + cl * dcv;
            dnm[l] = dn > EPSV ? dn : EPSV;
        }
    }

    // Phase inter: u = rq*Ssin, w = rq*Scos  (4l x 4d register tile)
    const int tl = tid >> 4, td = tid & 15;
    const int l0 = tl * 4, d0 = td * 4;
    float uu[4][4], wwv[4][4];
    #pragma unroll
    for (int r = 0; r < 4; ++r)
        #pragma unroll
        for (int x = 0; x < 4; ++x) { uu[r][x] = 0.f; wwv[r][x] = 0.f; }
    for (int dp = 0; dp < 64; ++dp) {
        float4 ss = *(const float4*)&S[dp * 64 + d0];
        float4 sc = *(const float4*)&S[(64 + dp) * 64 + d0];
        #pragma unroll
        for (int r = 0; r < 4; ++r) {
            float qv = rq[(l0 + r) * SD + dp];
            uu[r][0] += qv * ss.x;  uu[r][1] += qv * ss.y;
            uu[r][2] += qv * ss.z;  uu[r][3] += qv * ss.w;
            wwv[r][0] += qv * sc.x; wwv[r][1] += qv * sc.y;
            wwv[r][2] += qv * sc.z; wwv[r][3] += qv * sc.w;
        }
    }
    __syncthreads();   // Am + dnm now visible

    // Phase C: intra A*V
    float oo[4][4];
    #pragma unroll
    for (int r = 0; r < 4; ++r)
        #pragma unroll
        for (int x = 0; x < 4; ++x) oo[r][x] = 0.f;
    for (int j = 0; j < Cc; ++j) {
        float4 vj = *(const float4*)&vv[j * SD + d0];
        #pragma unroll
        for (int r = 0; r < 4; ++r) {
            float av = Am[(l0 + r) * SD + j];
            oo[r][0] += av * vj.x; oo[r][1] += av * vj.y;
            oo[r][2] += av * vj.z; oo[r][3] += av * vj.w;
        }
    }
    #pragma unroll
    for (int r = 0; r < 4; ++r) {
        int l = l0 + r;
        float sl = wsn[l], cl = wcs[l];
        float inv = 1.0f / dnm[l];
        float4 res;
        res.x = (oo[r][0] + sl * uu[r][0] + cl * wwv[r][0]) * inv;
        res.y = (oo[r][1] + sl * uu[r][1] + cl * wwv[r][1]) * inv;
        res.z = (oo[r][2] + sl * uu[r][2] + cl * wwv[r][2]) * inv;
        res.w = (oo[r][3] + sl * uu[r][3] + cl * wwv[r][3]) * inv;
        *(float4*)&out[gbase + (size_t)l * Dd + d0] = res;
    }
}

extern "C" void kernel_launch(void* const* d_in, const int* in_sizes, int n_in,
                              void* d_out, int out_size, void* d_ws, size_t ws_size,
                              hipStream_t stream) {
    const float* q = (const float*)d_in[0];
    const float* k = (const float*)d_in[1];
    const float* v = (const float*)d_in[2];
    float* out = (float*)d_out;
    float* ws = (float*)d_ws;   // needs (KV_TOTAL + 16*16*128)*4 B ~= 8.2 MB
    dim3 grid(NCHUNK, Hh);
    cosformer_chunk_sums<<<grid, 256, 0, stream>>>(k, v, ws);
    cosformer_chunk_out<<<grid, 256, 0, stream>>>(q, k, v, ws, out);
}

// Round 2
// 92.334 us; speedup vs baseline: 1.1230x; 1.1230x over previous
//
#include <hip/hip_runtime.h>

namespace {
constexpr int Hh = 16;
constexpr int Ll = 1024;
constexpr int Dd = 64;
constexpr int Cc = 64;                  // chunk length
constexpr int NCHUNK = Ll / Cc;         // 16
constexpr int SD = 68;                  // padded stride (16B-aligned, conflict-light)
constexpr int KV_CHUNK = 128 * 64;      // floats per chunk state
constexpr int KV_TOTAL = Hh * NCHUNK * KV_CHUNK;
constexpr float PI_HALF = 1.5707963267948966f;
constexpr float EPSV = 1e-6f;
}

// ---------------------------------------------------------------------------
// Kernel 1: per (head, chunk) sums  KV[f][d] = sum_j w[j]*rk[j][f]*v[j][d],
// ksum[f] = sum_j w[j]*rk[j][f]   (f<64: w=sin, f>=64: w=cos; rk = relu(k))
__global__ __launch_bounds__(256)
void cosformer_chunk_sums(const float* __restrict__ kin,
                          const float* __restrict__ vin,
                          float* __restrict__ ws) {
    const int c = blockIdx.x, h = blockIdx.y;
    const int tid = threadIdx.x;
    __shared__ float rk[Cc * SD];
    __shared__ float vv[Cc * SD];
    __shared__ float wsn[Cc], wcs[Cc];

    const size_t gbase = ((size_t)h * Ll + (size_t)c * Cc) * Dd;
    #pragma unroll
    for (int i = 0; i < (Cc * Dd) / 256; ++i) {
        int e = i * 256 + tid;
        int j = e >> 6, d = e & 63;
        float kx = kin[gbase + e];
        rk[j * SD + d] = kx > 0.f ? kx : 0.f;
        vv[j * SD + d] = vin[gbase + e];
    }
    if (tid < Cc) {
        float th = PI_HALF * (float)(c * Cc + tid + 1) * (1.0f / (float)Ll);
        wsn[tid] = __sinf(th);
        wcs[tid] = __cosf(th);
    }
    __syncthreads();

    // thread tile: 8 f x 4 d
    const int tf = tid >> 4;      // 0..15
    const int td = tid & 15;      // 0..15
    const int f0 = tf * 8;        // 0..120
    const int fi = f0 & 63;
    const float* wp = (f0 < 64) ? wsn : wcs;

    float acc[8][4];
    #pragma unroll
    for (int r = 0; r < 8; ++r)
        #pragma unroll
        for (int x = 0; x < 4; ++x) acc[r][x] = 0.f;

    for (int j = 0; j < Cc; ++j) {
        float w = wp[j];
        const float4 va = *(const float4*)&vv[j * SD + td * 4];
        const float4 b0 = *(const float4*)&rk[j * SD + fi];
        const float4 b1 = *(const float4*)&rk[j * SD + fi + 4];
        float wk[8] = {w * b0.x, w * b0.y, w * b0.z, w * b0.w,
                       w * b1.x, w * b1.y, w * b1.z, w * b1.w};
        #pragma unroll
        for (int r = 0; r < 8; ++r) {
            acc[r][0] += wk[r] * va.x;
            acc[r][1] += wk[r] * va.y;
            acc[r][2] += wk[r] * va.z;
            acc[r][3] += wk[r] * va.w;
        }
    }
    float* kvout = ws + (size_t)(h * NCHUNK + c) * KV_CHUNK;
    #pragma unroll
    for (int r = 0; r < 8; ++r) {
        *(float4*)&kvout[(f0 + r) * Dd + td * 4] =
            make_float4(acc[r][0], acc[r][1], acc[r][2], acc[r][3]);
    }
    if (tid < 128) {
        const float* wp2 = (tid < 64) ? wsn : wcs;
        int f = tid & 63;
        float s = 0.f;
        #pragma unroll 4
        for (int j = 0; j < Cc; ++j) s += wp2[j] * rk[j * SD + f];
        ws[(size_t)KV_TOTAL + (size_t)(h * NCHUNK + c) * 128 + tid] = s;
    }
}

// ---------------------------------------------------------------------------
// Kernel 1.5: in-place EXCLUSIVE prefix scan over the 16 chunk states (and
// ksums) of each head. Each thread owns one state element across all chunks.
// grid = (33, Hh): bx<32 -> state slice (256 elems each), bx==32 -> ksum.
__global__ __launch_bounds__(256)
void cosformer_scan(float* __restrict__ ws) {
    const int bx = blockIdx.x, h = blockIdx.y;
    const int tid = threadIdx.x;
    if (bx < 32) {
        const int e = bx * 256 + tid;               // 0..8191
        float* p = ws + (size_t)h * NCHUNK * KV_CHUNK + e;
        float run = 0.f;
        #pragma unroll
        for (int c = 0; c < NCHUNK; ++c) {
            float v = p[(size_t)c * KV_CHUNK];
            p[(size_t)c * KV_CHUNK] = run;
            run += v;
        }
    } else if (tid < 128) {
        float* p = ws + (size_t)KV_TOTAL + (size_t)h * NCHUNK * 128 + tid;
        float run = 0.f;
        #pragma unroll
        for (int c = 0; c < NCHUNK; ++c) {
            float v = p[c * 128];
            p[c * 128] = run;
            run += v;
        }
    }
}

// ---------------------------------------------------------------------------
// Kernel 2: per (head, chunk) output. Reads ONE exclusive prefix state.
__global__ __launch_bounds__(256)
void cosformer_chunk_out(const float* __restrict__ qin,
                         const float* __restrict__ kin,
                         const float* __restrict__ vin,
                         const float* __restrict__ ws,
                         float* __restrict__ out) {
    const int c = blockIdx.x, h = blockIdx.y;
    const int tid = threadIdx.x;
    __shared__ float rqT[Dd * SD];       // [d][l]
    __shared__ float rkT[Dd * SD];       // [d][j]
    __shared__ float vv[Cc * SD];        // [j][d]
    __shared__ float S[128 * 64];        // prefix state [f][d], stride 64
    __shared__ float AT[Cc * SD];        // scores transposed [j][l], masked
    __shared__ float ksum[128];
    __shared__ float wsn[Cc], wcs[Cc], dnm[Cc];

    const size_t gbase = ((size_t)h * Ll + (size_t)c * Cc) * Dd;

    // ---- staging ----
    {
        const float4* q4 = (const float4*)(qin + gbase);
        const float4* k4 = (const float4*)(kin + gbase);
        const float4* v4 = (const float4*)(vin + gbase);
        #pragma unroll
        for (int i = 0; i < 4; ++i) {
            int e4 = i * 256 + tid;          // float4 index over 64x64
            int j = e4 >> 4;                 // row
            int d4 = (e4 & 15) * 4;          // col
            float4 qv = q4[e4];
            rqT[(d4 + 0) * SD + j] = qv.x > 0.f ? qv.x : 0.f;
            rqT[(d4 + 1) * SD + j] = qv.y > 0.f ? qv.y : 0.f;
            rqT[(d4 + 2) * SD + j] = qv.z > 0.f ? qv.z : 0.f;
            rqT[(d4 + 3) * SD + j] = qv.w > 0.f ? qv.w : 0.f;
            float4 kv = k4[e4];
            rkT[(d4 + 0) * SD + j] = kv.x > 0.f ? kv.x : 0.f;
            rkT[(d4 + 1) * SD + j] = kv.y > 0.f ? kv.y : 0.f;
            rkT[(d4 + 2) * SD + j] = kv.z > 0.f ? kv.z : 0.f;
            rkT[(d4 + 3) * SD + j] = kv.w > 0.f ? kv.w : 0.f;
            *(float4*)&vv[j * SD + d4] = v4[e4];
        }
        const float4* sp4 = (const float4*)(ws + (size_t)(h * NCHUNK + c) * KV_CHUNK);
        #pragma unroll
        for (int i = 0; i < 8; ++i) {
            int e4 = i * 256 + tid;
            ((float4*)S)[e4] = sp4[e4];
        }
        if (tid < 128)
            ksum[tid] = ws[(size_t)KV_TOTAL + (size_t)(h * NCHUNK + c) * 128 + tid];
        if (tid < Cc) {
            float th = PI_HALF * (float)(c * Cc + tid + 1) * (1.0f / (float)Ll);
            wsn[tid] = __sinf(th);
            wcs[tid] = __cosf(th);
        }
    }
    __syncthreads();

    // ---- Phase A: causal scores -> AT[j][l] (masked entries = 0) ----
    {
        const int tl = tid & 15, tj = tid >> 4;
        const int l0 = tl * 4, j0 = tj * 4;
        float acc[4][4];
        #pragma unroll
        for (int r = 0; r < 4; ++r)
            #pragma unroll
            for (int x = 0; x < 4; ++x) acc[r][x] = 0.f;
        if (j0 <= l0 + 3) {
            for (int dp = 0; dp < Dd; ++dp) {
                float4 a = *(const float4*)&rqT[dp * SD + l0];
                float4 b = *(const float4*)&rkT[dp * SD + j0];
                acc[0][0] += a.x * b.x; acc[0][1] += a.x * b.y;
                acc[0][2] += a.x * b.z; acc[0][3] += a.x * b.w;
                acc[1][0] += a.y * b.x; acc[1][1] += a.y * b.y;
                acc[1][2] += a.y * b.z; acc[1][3] += a.y * b.w;
                acc[2][0] += a.z * b.x; acc[2][1] += a.z * b.y;
                acc[2][2] += a.z * b.z; acc[2][3] += a.z * b.w;
                acc[3][0] += a.w * b.x; acc[3][1] += a.w * b.y;
                acc[3][2] += a.w * b.z; acc[3][3] += a.w * b.w;
            }
        }
        #pragma unroll
        for (int x = 0; x < 4; ++x) {
            int j = j0 + x;
            float sj = wsn[j], cj = wcs[j];
            float4 col;
            float* cp = &col.x;
            #pragma unroll
            for (int r = 0; r < 4; ++r) {
                int l = l0 + r;
                float w = wsn[l] * sj + wcs[l] * cj;
                cp[r] = (j <= l) ? acc[r][x] * w : 0.f;
            }
            *(float4*)&AT[j * SD + l0] = col;
        }
    }
    __syncthreads();

    // ---- Denominator (one thread per row) + Phase inter (all threads) ----
    if (tid < Cc) {
        const int l = tid;
        float rs = 0.f;
        #pragma unroll 4
        for (int j = 0; j < Cc; ++j) rs += AT[j * SD + l];
        float dsv = 0.f, dcv = 0.f;
        #pragma unroll 4
        for (int dp = 0; dp < Dd; ++dp) {
            float qv = rqT[dp * SD + l];
            dsv += qv * ksum[dp];
            dcv += qv * ksum[64 + dp];
        }
        float dn = rs + wsn[l] * dsv + wcs[l] * dcv;
        dnm[l] = dn > EPSV ? dn : EPSV;
    }

    const int l0 = (tid >> 4) * 4;
    const int d0 = (tid & 15) * 4;
    float uu[4][4], wwv[4][4];
    #pragma unroll
    for (int r = 0; r < 4; ++r)
        #pragma unroll
        for (int x = 0; x < 4; ++x) { uu[r][x] = 0.f; wwv[r][x] = 0.f; }
    for (int dp = 0; dp < Dd; ++dp) {
        float4 a = *(const float4*)&rqT[dp * SD + l0];
        float4 ss = *(const float4*)&S[dp * 64 + d0];
        float4 sc = *(const float4*)&S[(64 + dp) * 64 + d0];
        const float* ap = &a.x;
        #pragma unroll
        for (int r = 0; r < 4; ++r) {
            float qv = ap[r];
            uu[r][0] += qv * ss.x;  uu[r][1] += qv * ss.y;
            uu[r][2] += qv * ss.z;  uu[r][3] += qv * ss.w;
            wwv[r][0] += qv * sc.x; wwv[r][1] += qv * sc.y;
            wwv[r][2] += qv * sc.z; wwv[r][3] += qv * sc.w;
        }
    }
    __syncthreads();   // dnm visible; AT stable

    // ---- Phase C: intra A*V ----
    float oo[4][4];
    #pragma unroll
    for (int r = 0; r < 4; ++r)
        #pragma unroll
        for (int x = 0; x < 4; ++x) oo[r][x] = 0.f;
    for (int j = 0; j < Cc; ++j) {
        float4 a = *(const float4*)&AT[j * SD + l0];
        float4 vj = *(const float4*)&vv[j * SD + d0];
        const float* ap = &a.x;
        #pragma unroll
        for (int r = 0; r < 4; ++r) {
            float av = ap[r];
            oo[r][0] += av * vj.x; oo[r][1] += av * vj.y;
            oo[r][2] += av * vj.z; oo[r][3] += av * vj.w;
        }
    }
    #pragma unroll
    for (int r = 0; r < 4; ++r) {
        int l = l0 + r;
        float sl = wsn[l], cl = wcs[l];
        float inv = 1.0f / dnm[l];
        float4 res;
        res.x = (oo[r][0] + sl * uu[r][0] + cl * wwv[r][0]) * inv;
        res.y = (oo[r][1] + sl * uu[r][1] + cl * wwv[r][1]) * inv;
        res.z = (oo[r][2] + sl * uu[r][2] + cl * wwv[r][2]) * inv;
        res.w = (oo[r][3] + sl * uu[r][3] + cl * wwv[r][3]) * inv;
        *(float4*)&out[gbase + (size_t)l * Dd + d0] = res;
    }
}

extern "C" void kernel_launch(void* const* d_in, const int* in_sizes, int n_in,
                              void* d_out, int out_size, void* d_ws, size_t ws_size,
                              hipStream_t stream) {
    const float* q = (const float*)d_in[0];
    const float* k = (const float*)d_in[1];
    const float* v = (const float*)d_in[2];
    float* out = (float*)d_out;
    float* ws = (float*)d_ws;   // uses (KV_TOTAL + 16*16*128)*4 B ~= 8.5 MB
    dim3 grid(NCHUNK, Hh);
    cosformer_chunk_sums<<<grid, 256, 0, stream>>>(k, v, ws);
    cosformer_scan<<<dim3(33, Hh), 256, 0, stream>>>(ws);
    cosformer_chunk_out<<<grid, 256, 0, stream>>>(q, k, v, ws, out);
}

// Round 3
// 77.013 us; speedup vs baseline: 1.3465x; 1.1989x over previous
//
#include <hip/hip_runtime.h>

namespace {
constexpr int Hh = 16;
constexpr int Ll = 1024;
constexpr int Dd = 64;
constexpr int Cc = 64;                   // chunk length
constexpr int NCHUNK = Ll / Cc;          // 16
constexpr float PI_HALF = 1.5707963267948966f;
constexpr float EPSV = 1e-6f;
constexpr int KV_ELEMS = 128 * 64;       // bf16 elems per chunk state [d][f]
constexpr size_t KV_TOTAL_E = (size_t)Hh * NCHUNK * KV_ELEMS;
}

typedef __attribute__((ext_vector_type(8))) short short8;
typedef __attribute__((ext_vector_type(4))) float floatx4;

__device__ __forceinline__ unsigned short f2bf(float x) {
    unsigned int u = __float_as_uint(x);
    unsigned int r = u + 0x7fffu + ((u >> 16) & 1u);
    return (unsigned short)(r >> 16);
}
__device__ __forceinline__ float bf2f(unsigned short b) {
    return __uint_as_float(((unsigned int)b) << 16);
}

// ---------------------------------------------------------------------------
// Kernel 1: per (h,c) chunk sums via MFMA.
//   C[f][d] = sum_j kf[j][f] * v[j][d],  kf[j][f] = relu(k)[j][f&63]*(f<64?s_j:c_j)
//   ksum[f] = sum_j kf[j][f]  (ones-column of B)
// A = kf^T stored [f][j] (stride 72), B = [V | 1] stored [n=d][k=j] (stride 72).
// Output staged to LDS as [d][f] then coalesced bf16 store to ws.
__global__ __launch_bounds__(256)
void cf_sums(const float* __restrict__ kin, const float* __restrict__ vin,
             unsigned short* __restrict__ wskv, unsigned short* __restrict__ wsks) {
    const int c = blockIdx.x, h = blockIdx.y;
    const int tid = threadIdx.x;
    constexpr int S1 = 72, SC = 136;
    __shared__ unsigned short Ak[128 * S1];
    __shared__ unsigned short Bv1[80 * S1];
    __shared__ unsigned short Cst[64 * SC];
    __shared__ unsigned short Ks[128];

    const size_t gbase = ((size_t)h * Ll + (size_t)c * Cc) * Dd;
    const float4* k4 = (const float4*)(kin + gbase);
    const float4* v4 = (const float4*)(vin + gbase);
    #pragma unroll
    for (int i = 0; i < 4; ++i) {
        int e4 = i * 256 + tid;
        int j = e4 >> 4, d4 = (e4 & 15) * 4;
        float th = PI_HALF * (float)(c * Cc + j + 1) * (1.0f / (float)Ll);
        float sj, cj; __sincosf(th, &sj, &cj);
        float4 kx = k4[e4];
        float r0 = fmaxf(kx.x, 0.f), r1 = fmaxf(kx.y, 0.f);
        float r2 = fmaxf(kx.z, 0.f), r3 = fmaxf(kx.w, 0.f);
        Ak[(d4 + 0) * S1 + j] = f2bf(r0 * sj);
        Ak[(d4 + 1) * S1 + j] = f2bf(r1 * sj);
        Ak[(d4 + 2) * S1 + j] = f2bf(r2 * sj);
        Ak[(d4 + 3) * S1 + j] = f2bf(r3 * sj);
        Ak[(64 + d4 + 0) * S1 + j] = f2bf(r0 * cj);
        Ak[(64 + d4 + 1) * S1 + j] = f2bf(r1 * cj);
        Ak[(64 + d4 + 2) * S1 + j] = f2bf(r2 * cj);
        Ak[(64 + d4 + 3) * S1 + j] = f2bf(r3 * cj);
        float4 vx = v4[e4];
        Bv1[(d4 + 0) * S1 + j] = f2bf(vx.x);
        Bv1[(d4 + 1) * S1 + j] = f2bf(vx.y);
        Bv1[(d4 + 2) * S1 + j] = f2bf(vx.z);
        Bv1[(d4 + 3) * S1 + j] = f2bf(vx.w);
    }
    if (tid < 64) Bv1[64 * S1 + tid] = 0x3F80;           // ones column (bf16 1.0)
    if (tid >= 64 && tid < 72) Bv1[64 * S1 + tid] = 0;   // pad of ones row
    #pragma unroll
    for (int i = 0; i < 3; ++i) {                        // zero rows 65..79
        int z = i * 256 + tid;
        if (z < 540) ((unsigned int*)Bv1)[(65 * S1) / 2 + z] = 0u;
    }
    __syncthreads();

    const int wave = tid >> 6, lane = tid & 63;
    const int lrow = lane & 15, quad = lane >> 4;
    #pragma unroll
    for (int t = 0; t < 2; ++t) {
        const int ft = wave * 2 + t;                     // f-tile 0..7
        short8 af[2];
        #pragma unroll
        for (int ks = 0; ks < 2; ++ks)
            af[ks] = *(const short8*)&Ak[(ft * 16 + lrow) * S1 + ks * 32 + quad * 8];
        #pragma unroll
        for (int nt = 0; nt < 5; ++nt) {
            floatx4 acc = {0.f, 0.f, 0.f, 0.f};
            #pragma unroll
            for (int ks = 0; ks < 2; ++ks) {
                short8 bf = *(const short8*)&Bv1[(nt * 16 + lrow) * S1 + ks * 32 + quad * 8];
                acc = __builtin_amdgcn_mfma_f32_16x16x32_bf16(af[ks], bf, acc, 0, 0, 0);
            }
            ushort4 pk = make_ushort4(f2bf(acc[0]), f2bf(acc[1]), f2bf(acc[2]), f2bf(acc[3]));
            if (nt < 4) {
                // C[f][d] -> Cst[d][f]; rows f = ft*16+quad*4+r contiguous in f
                *(ushort4*)&Cst[(nt * 16 + lrow) * SC + ft * 16 + quad * 4] = pk;
            } else if (lrow == 0) {
                *(ushort4*)&Ks[ft * 16 + quad * 4] = pk;  // ksum column (n=64)
            }
        }
    }
    __syncthreads();

    unsigned short* kvout = wskv + (size_t)(h * NCHUNK + c) * KV_ELEMS;
    #pragma unroll
    for (int i = 0; i < 4; ++i) {
        int idx = i * 256 + tid;
        int row = idx >> 4, c8 = (idx & 15) * 8;
        *(uint4*)(kvout + row * 128 + c8) = *(const uint4*)&Cst[row * SC + c8];
    }
    if (tid < 16)
        *(uint4*)(wsks + (size_t)(h * NCHUNK + c) * 128 + tid * 8) =
            *(const uint4*)&Ks[tid * 8];
}

// ---------------------------------------------------------------------------
// Kernel 1.5: in-place EXCLUSIVE prefix scan across chunks (fp32 accumulate,
// bf16 store). bx<32 -> state elements; bx==32 -> ksums.
__global__ __launch_bounds__(256)
void cf_scan(unsigned short* __restrict__ wskv, unsigned short* __restrict__ wsks) {
    const int bx = blockIdx.x, h = blockIdx.y;
    const int tid = threadIdx.x;
    if (bx < 32) {
        unsigned short* p = wskv + (size_t)h * NCHUNK * KV_ELEMS + bx * 256 + tid;
        float run = 0.f;
        #pragma unroll
        for (int cc = 0; cc < NCHUNK; ++cc) {
            float v = bf2f(p[(size_t)cc * KV_ELEMS]);
            p[(size_t)cc * KV_ELEMS] = f2bf(run);
            run += v;
        }
    } else if (tid < 128) {
        unsigned short* p = wsks + (size_t)h * NCHUNK * 128 + tid;
        float run = 0.f;
        #pragma unroll
        for (int cc = 0; cc < NCHUNK; ++cc) {
            float v = bf2f(p[cc * 128]);
            p[cc * 128] = f2bf(run);
            run += v;
        }
    }
}

// ---------------------------------------------------------------------------
// Kernel 2: per (h,c) output, all-MFMA. Wave w owns l-tile w end to end.
//  GEMM1: D1[64 x 80] = qf[64 x 128] * BkT, cols 0..63 = scores, col 64 = qf*ksum
//  mask+rowsum -> denominator (register shfl reduce); masked scores -> Aq cols 0..63
//  GEMM2: O[64 x 64] = [scores | qf] (K=192) * [V ; S]
__global__ __launch_bounds__(256)
void cf_out(const float* __restrict__ qin, const float* __restrict__ kin,
            const float* __restrict__ vin,
            const unsigned short* __restrict__ wskv,
            const unsigned short* __restrict__ wsks,
            float* __restrict__ out) {
    const int c = blockIdx.x, h = blockIdx.y;
    const int tid = threadIdx.x;
    constexpr int SA = 200, SB = 136, SV = 200;
    __shared__ unsigned short Aq[64 * SA];   // [l][0..63 scores | 64..191 qf]
    __shared__ unsigned short Bk[80 * SB];   // [n=j][k=f]; row 64 = ksum; 65..79 = 0
    __shared__ unsigned short Bv[64 * SV];   // [n=d][0..63 V^T | 64..191 S^T]

    const size_t gbase = ((size_t)h * Ll + (size_t)c * Cc) * Dd;
    const float4* q4 = (const float4*)(qin + gbase);
    const float4* k4 = (const float4*)(kin + gbase);
    const float4* v4 = (const float4*)(vin + gbase);
    #pragma unroll
    for (int i = 0; i < 4; ++i) {
        int e4 = i * 256 + tid;
        int j = e4 >> 4, d4 = (e4 & 15) * 4;
        float th = PI_HALF * (float)(c * Cc + j + 1) * (1.0f / (float)Ll);
        float sj, cj; __sincosf(th, &sj, &cj);
        float4 qv = q4[e4];
        float q0 = fmaxf(qv.x, 0.f), q1 = fmaxf(qv.y, 0.f);
        float q2 = fmaxf(qv.z, 0.f), q3 = fmaxf(qv.w, 0.f);
        *(ushort4*)&Aq[j * SA + 64 + d4] =
            make_ushort4(f2bf(q0 * sj), f2bf(q1 * sj), f2bf(q2 * sj), f2bf(q3 * sj));
        *(ushort4*)&Aq[j * SA + 128 + d4] =
            make_ushort4(f2bf(q0 * cj), f2bf(q1 * cj), f2bf(q2 * cj), f2bf(q3 * cj));
        float4 kx = k4[e4];
        float k0 = fmaxf(kx.x, 0.f), k1 = fmaxf(kx.y, 0.f);
        float k2 = fmaxf(kx.z, 0.f), k3 = fmaxf(kx.w, 0.f);
        *(ushort4*)&Bk[j * SB + d4] =
            make_ushort4(f2bf(k0 * sj), f2bf(k1 * sj), f2bf(k2 * sj), f2bf(k3 * sj));
        *(ushort4*)&Bk[j * SB + 64 + d4] =
            make_ushort4(f2bf(k0 * cj), f2bf(k1 * cj), f2bf(k2 * cj), f2bf(k3 * cj));
        float4 vx = v4[e4];
        Bv[(d4 + 0) * SV + j] = f2bf(vx.x);
        Bv[(d4 + 1) * SV + j] = f2bf(vx.y);
        Bv[(d4 + 2) * SV + j] = f2bf(vx.z);
        Bv[(d4 + 3) * SV + j] = f2bf(vx.w);
    }
    // S state: ws [d][f] -> Bv[d][64+f] (b128 copies)
    const uint4* s4 = (const uint4*)(wskv + (size_t)(h * NCHUNK + c) * KV_ELEMS);
    #pragma unroll
    for (int i = 0; i < 4; ++i) {
        int idx = i * 256 + tid;
        int d = idx >> 4, f8 = (idx & 15) * 8;
        *(uint4*)&Bv[d * SV + 64 + f8] = s4[idx];
    }
    if (tid < 16)
        *(uint4*)&Bk[64 * SB + tid * 8] =
            ((const uint4*)(wsks + (size_t)(h * NCHUNK + c) * 128))[tid];
    #pragma unroll
    for (int i = 0; i < 4; ++i) {                        // zero Bk rows 65..79
        int z = i * 256 + tid;
        if (z < 1020) ((unsigned int*)Bk)[(65 * SB) / 2 + z] = 0u;
    }
    __syncthreads();

    const int wave = tid >> 6, lane = tid & 63;
    const int lrow = lane & 15, quad = lane >> 4;
    const int l0 = wave * 16;
    const int arow = (l0 + lrow) * SA;

    // ---- GEMM1: scores + denominator ----
    short8 a1[4];
    #pragma unroll
    for (int ks = 0; ks < 4; ++ks)
        a1[ks] = *(const short8*)&Aq[arow + 64 + ks * 32 + quad * 8];
    floatx4 rs = {0.f, 0.f, 0.f, 0.f};
    #pragma unroll
    for (int nt = 0; nt < 5; ++nt) {
        floatx4 acc = {0.f, 0.f, 0.f, 0.f};
        #pragma unroll
        for (int ks = 0; ks < 4; ++ks) {
            short8 bf = *(const short8*)&Bk[(nt * 16 + lrow) * SB + ks * 32 + quad * 8];
            acc = __builtin_amdgcn_mfma_f32_16x16x32_bf16(a1[ks], bf, acc, 0, 0, 0);
        }
        if (nt < 4) {
            int j = nt * 16 + lrow;
            #pragma unroll
            for (int r = 0; r < 4; ++r) {
                int l = l0 + quad * 4 + r;
                float m = (j <= l) ? acc[r] : 0.f;
                acc[r] = m;
                Aq[l * SA + j] = f2bf(m);      // masked score -> A-layout for GEMM2
            }
        }
        rs += acc;                              // nt==4: cols 65..79 are exact zeros
    }
    #pragma unroll
    for (int m = 1; m <= 8; m <<= 1) {          // row-sum across the 16 cols
        rs[0] += __shfl_xor(rs[0], m);
        rs[1] += __shfl_xor(rs[1], m);
        rs[2] += __shfl_xor(rs[2], m);
        rs[3] += __shfl_xor(rs[3], m);
    }
    float inv[4];
    #pragma unroll
    for (int r = 0; r < 4; ++r) inv[r] = 1.0f / fmaxf(rs[r], EPSV);

    __syncthreads();   // make this wave's score writes unambiguously visible

    // ---- GEMM2: O = [scores | qf] * [V ; S] ----
    short8 s0 = *(const short8*)&Aq[arow + 0 * 32 + quad * 8];
    short8 s1 = *(const short8*)&Aq[arow + 1 * 32 + quad * 8];
    #pragma unroll
    for (int nt = 0; nt < 4; ++nt) {
        const int brow = (nt * 16 + lrow) * SV;
        floatx4 acc = {0.f, 0.f, 0.f, 0.f};
        short8 b0 = *(const short8*)&Bv[brow + 0 * 32 + quad * 8];
        acc = __builtin_amdgcn_mfma_f32_16x16x32_bf16(s0, b0, acc, 0, 0, 0);
        short8 b1 = *(const short8*)&Bv[brow + 1 * 32 + quad * 8];
        acc = __builtin_amdgcn_mfma_f32_16x16x32_bf16(s1, b1, acc, 0, 0, 0);
        #pragma unroll
        for (int ks = 2; ks < 6; ++ks) {
            short8 bf = *(const short8*)&Bv[brow + ks * 32 + quad * 8];
            acc = __builtin_amdgcn_mfma_f32_16x16x32_bf16(a1[ks - 2], bf, acc, 0, 0, 0);
        }
        #pragma unroll
        for (int r = 0; r < 4; ++r) {
            int l = l0 + quad * 4 + r;
            out[gbase + (size_t)l * Dd + nt * 16 + lrow] = acc[r] * inv[r];
        }
    }
}

extern "C" void kernel_launch(void* const* d_in, const int* in_sizes, int n_in,
                              void* d_out, int out_size, void* d_ws, size_t ws_size,
                              hipStream_t stream) {
    const float* q = (const float*)d_in[0];
    const float* k = (const float*)d_in[1];
    const float* v = (const float*)d_in[2];
    float* out = (float*)d_out;
    unsigned short* wskv = (unsigned short*)d_ws;             // [h][c][d][f] bf16
    unsigned short* wsks = wskv + KV_TOTAL_E;                 // [h][c][128] bf16
    dim3 grid(NCHUNK, Hh);
    cf_sums<<<grid, 256, 0, stream>>>(k, v, wskv, wsks);
    cf_scan<<<dim3(33, Hh), 256, 0, stream>>>(wskv, wsks);
    cf_out<<<grid, 256, 0, stream>>>(q, k, v, wskv, wsks, out);
}